// Round 2
// baseline (89.891 us; speedup 1.0000x reference)
//
#include <hip/hip_runtime.h>
#include <stdint.h>

#define NQ 1000
#define NGT 32
#define BS 4
#define NSP 100
#define MNUM 13
#define NPAIR (NGT * MNUM)   // 416
#define MAGIC 0x5A5A5A5Au

// ws layout (uint32 words):
//   per-column sel block: col c = b*32+g at ws + c*32:
//     words [0..12]  : selected query indices (ascending by (cost,q) rank order)
//     words [16..28] : f2sort(cost) keys for those queries
//   flags: ws + FLAG_BASE + c  (MAGIC when column c published)
#define SEL_WORDS 32
#define FLAG_BASE (128 * SEL_WORDS)

__device__ __forceinline__ unsigned int f2sort(float f) {
    unsigned int u = __float_as_uint(f);
    return (u & 0x80000000u) ? ~u : (u | 0x80000000u);
}

__global__ __launch_bounds__(256) void fused_matcher_kernel(
    const float* __restrict__ logits,   // [BS, NQ, 1]
    const float* __restrict__ pbez,     // [BS, NQ, 8]
    const float* __restrict__ tbez,     // [BS, NGT, 4, 2]
    unsigned int* __restrict__ ws,
    int* __restrict__ out)              // [BS*NPAIR src | BS*NPAIR tgt | BS counts]
{
    const int blk = blockIdx.x;         // b*NGT + g
    const int b = blk >> 5;
    const int g = blk & 31;
    const int tid = threadIdx.x;

    __shared__ float bas[NSP][4];       // Bernstein basis
    __shared__ float tp[2 * NSP];       // this column's target sample points
    __shared__ float colC[NQ];          // this column's costs
    __shared__ int          selq_s[MNUM];
    __shared__ unsigned int selk_s[MNUM];
    __shared__ unsigned long long key[NQ];   // assembler only
    __shared__ int cnts[256];
    __shared__ int offs[257];

    // ---- Phase A: basis + target points for (b, g) ----
    if (tid < NSP) {
        const float t   = (float)tid * (1.0f / 99.0f);
        const float omt = 1.0f - t;
        const float b0 = omt * omt * omt;
        const float b1 = 3.0f * t * omt * omt;
        const float b2 = 3.0f * t * t * omt;
        const float b3 = t * t * t;
        bas[tid][0] = b0; bas[tid][1] = b1; bas[tid][2] = b2; bas[tid][3] = b3;
        const float* c8 = tbez + ((size_t)b * NGT + g) * 8;
        tp[2 * tid]     = b0 * c8[0] + b1 * c8[2] + b2 * c8[4] + b3 * c8[6];
        tp[2 * tid + 1] = b0 * c8[1] + b1 * c8[3] + b2 * c8[5] + b3 * c8[7];
    }
    __syncthreads();

    // ---- Phase B: column costs (threads 0..249, 4 queries each) ----
    if (tid < 250) {
        float ctrl[4][8];
        const float4* pb = (const float4*)(pbez + ((size_t)b * NQ + tid * 4) * 8);
        #pragma unroll
        for (int k = 0; k < 4; ++k) {
            const float4 u = pb[2 * k], v = pb[2 * k + 1];
            ctrl[k][0] = u.x; ctrl[k][1] = u.y; ctrl[k][2] = u.z; ctrl[k][3] = u.w;
            ctrl[k][4] = v.x; ctrl[k][5] = v.y; ctrl[k][6] = v.z; ctrl[k][7] = v.w;
        }
        double acc[4] = {0.0, 0.0, 0.0, 0.0};
        for (int s = 0; s < NSP; ++s) {
            const float b0 = bas[s][0], b1 = bas[s][1], b2 = bas[s][2], b3 = bas[s][3];
            const float tx = tp[2 * s], ty = tp[2 * s + 1];
            #pragma unroll
            for (int k = 0; k < 4; ++k) {
                const float px = b0 * ctrl[k][0] + b1 * ctrl[k][2] + b2 * ctrl[k][4] + b3 * ctrl[k][6];
                const float py = b0 * ctrl[k][1] + b1 * ctrl[k][3] + b2 * ctrl[k][5] + b3 * ctrl[k][7];
                acc[k] += (double)fabsf(px - tx);
                acc[k] += (double)fabsf(py - ty);
            }
        }
        const float4 lg4 = *(const float4*)(logits + (size_t)b * NQ + tid * 4);
        const float lgs[4] = {lg4.x, lg4.y, lg4.z, lg4.w};
        #pragma unroll
        for (int k = 0; k < 4; ++k) {
            const float lg = lgs[k];
            float p;
            if (lg >= 0.0f) { p = 1.0f / (1.0f + expf(-lg)); }
            else            { const float e = expf(lg); p = e / (1.0f + e); }
            const float pos = 0.25f * (1.0f - p) * (1.0f - p) * (-logf(p + 1e-8f));
            const float neg = 0.75f * p * p * (-log1pf(-p + 1e-8f));
            colC[tid * 4 + k] = 2.0f * (pos - neg) + 5.0f * (float)acc[k];
        }
    }
    __syncthreads();

    // ---- Phase C: top-13 smallest of this column (wave 0) ----
    if (tid < 64) {
        unsigned long long loc[16];
        #pragma unroll
        for (int j = 0; j < 16; ++j) {
            const int q = j * 64 + tid;
            loc[j] = (q < NQ)
                ? (((unsigned long long)f2sort(colC[q]) << 32) | (unsigned int)q)
                : ~0ull;
        }
        for (int r = 0; r < MNUM; ++r) {
            unsigned long long m = loc[0];
            #pragma unroll
            for (int j = 1; j < 16; ++j) m = (loc[j] < m) ? loc[j] : m;
            #pragma unroll
            for (int off = 1; off < 64; off <<= 1) {
                const unsigned long long o = __shfl_xor(m, off, 64);
                m = (o < m) ? o : m;
            }
            const int q = (int)(m & 0xFFFFFFFFu);
            if (tid == (q & 63)) loc[q >> 6] = ~0ull;
            if (tid == 0) { selq_s[r] = q; selk_s[r] = (unsigned int)(m >> 32); }
        }
    }
    __syncthreads();

    // publish this column's selection to ws, then raise the flag
    unsigned int* selws = ws + blk * SEL_WORDS;
    if (tid < MNUM)                      selws[tid]      = (unsigned int)selq_s[tid];
    if (tid >= 16 && tid < 16 + MNUM)    selws[tid]      = selk_s[tid - 16];
    __threadfence();
    __syncthreads();
    if (tid == 0) atomicExch(ws + FLAG_BASE + blk, MAGIC);

    if (g != 0) return;

    // ---- Phase D: assembler (one block per batch) ----
    if (tid >= 1 && tid < NGT) {
        while (__hip_atomic_load(ws + FLAG_BASE + b * NGT + tid,
                                 __ATOMIC_RELAXED, __HIP_MEMORY_SCOPE_AGENT) != MAGIC) {
            __builtin_amdgcn_s_sleep(1);
        }
    }
    __syncthreads();
    __threadfence();

    for (int q = tid; q < NQ; q += 256) key[q] = ~0ull;
    __syncthreads();

    for (int j = tid; j < NPAIR; j += 256) {
        const int gg = j / MNUM, r = j % MNUM;
        const unsigned int* sw = ws + (b * NGT + gg) * SEL_WORDS;
        const unsigned int q   = sw[r];
        const unsigned int k32 = sw[16 + r];
        atomicMin(&key[q], ((unsigned long long)k32 << 32) | (unsigned int)gg);
    }
    __syncthreads();

    const int base = tid * 4;
    int lc = 0;
    for (int k = 0; k < 4; ++k) {
        const int q = base + k;
        if (q < NQ && key[q] != ~0ull) lc++;
    }
    cnts[tid] = lc;
    __syncthreads();
    if (tid == 0) {
        int run = 0;
        for (int i = 0; i < 256; ++i) { offs[i] = run; run += cnts[i]; }
        offs[256] = run;
    }
    __syncthreads();

    const int total = offs[256];
    int* src_out = out + b * NPAIR;
    int* tgt_out = out + BS * NPAIR + b * NPAIR;

    int pos = offs[tid];
    for (int k = 0; k < 4; ++k) {
        const int q = base + k;
        if (q < NQ && key[q] != ~0ull) {
            src_out[pos] = q;
            tgt_out[pos] = (int)(key[q] & 0xFFFFFFFFu);
            pos++;
        }
    }
    for (int i = total + tid; i < NPAIR; i += 256) {
        src_out[i] = NQ;     // padding sentinel = nq
        tgt_out[i] = -1;
    }
    if (tid == 0) out[2 * BS * NPAIR + b] = total;
}

extern "C" void kernel_launch(void* const* d_in, const int* in_sizes, int n_in,
                              void* d_out, int out_size, void* d_ws, size_t ws_size,
                              hipStream_t stream) {
    const float* logits = (const float*)d_in[0];   // [4,1000,1]
    const float* pbez   = (const float*)d_in[1];   // [4,1000,8]
    // d_in[2] = tgt_labels: nc==1 so every valid label is 0 -> unused
    const float* tbez   = (const float*)d_in[3];   // [4,32,4,2]

    fused_matcher_kernel<<<BS * NGT, 256, 0, stream>>>(
        logits, pbez, tbez, (unsigned int*)d_ws, (int*)d_out);
}